// Round 11
// baseline (331.019 us; speedup 1.0000x reference)
//
#include <hip/hip_runtime.h>
#include <hip/hip_fp16.h>

#define NN 50000
#define NE 800000
#define NEPAD (NE + NN + 16)   // even-padded CSR capacity
#define DIM 128
#define NEG_SLOPE 0.1f
#define CHUNK_U2 (NN * 8)      // uint2 elems per 32-col chunk

typedef int iv4 __attribute__((ext_vector_type(4)));   // native vec for nt-loads

// ---------- preprocessing (atomic-light CSR build) ----------

// count histogram; atomic return value = within-row slot (saved for atomic-free place)
__global__ void k_hist(const int* __restrict__ ei, int* __restrict__ hist,
                       int* __restrict__ slot) {
    int e = blockIdx.x * 256 + threadIdx.x;
    if (e >= NE) return;
    int d = ei[NE + e];
    slot[e] = atomicAdd(&hist[d], 1);
}

// scan1: per-block (1024 elems) exclusive scan of EVEN-PADDED counts -> rowptr,
// block sums -> aux.
__global__ void k_scan1(const int* __restrict__ hist, int* __restrict__ rowptr,
                        int* __restrict__ aux) {
    __shared__ int sdata[256];
    int t = threadIdx.x;
    int base = blockIdx.x * 1024 + t * 4;
    int v[4]; int s = 0;
    #pragma unroll
    for (int j = 0; j < 4; ++j) {
        v[j] = (base + j < NN) ? ((hist[base + j] + 1) & ~1) : 0;  // pad to even
        s += v[j];
    }
    sdata[t] = s;
    __syncthreads();
    for (int off = 1; off < 256; off <<= 1) {
        int x = (t >= off) ? sdata[t - off] : 0;
        __syncthreads();
        sdata[t] += x;
        __syncthreads();
    }
    int run = sdata[t] - s;
    if (t == 255) aux[blockIdx.x] = sdata[255];
    #pragma unroll
    for (int j = 0; j < 4; ++j) { if (base + j < NN) rowptr[base + j] = run; run += v[j]; }
}

// scan3 (fused): every block redundantly scans the 49 block sums, adds offset.
__global__ void k_scan3(int* __restrict__ rowptr, const int* __restrict__ aux) {
    __shared__ int exs[64];
    __shared__ int stot;
    int t = threadIdx.x;
    if (t < 64) {
        int v = (t < 49) ? aux[t] : 0;
        int orig = v;
        for (int off = 1; off < 64; off <<= 1) {
            int y = __shfl_up(v, off, 64);
            if (t >= off) v += y;
        }
        exs[t] = v - orig;
        if (t == 48) stot = v;
    }
    __syncthreads();
    int i = blockIdx.x * 256 + t;
    if (i < NN) rowptr[i] += exs[i >> 10];
    if (i == 0) rowptr[NN] = stot;
}

// atomic-free placement: epack[rowptr[d] + slot[e]] = {src, w}
__global__ void k_place(const int* __restrict__ ei, const float* __restrict__ attr,
                        const int* __restrict__ etype, const float* __restrict__ scale,
                        const int* __restrict__ rowptr, const int* __restrict__ slot,
                        int2* __restrict__ epack) {
    int e = blockIdx.x * 256 + threadIdx.x;
    if (e >= NE) return;
    int s = ei[e], d = ei[NE + e];
    float w = scale[etype[e]] * attr[e];
    int2 pk; pk.x = s; pk.y = __float_as_int(w);
    epack[rowptr[d] + slot[e]] = pk;
}

// deg via segmented sum of placed coefs (padding slots are 0); dinv = rsqrt(deg)
__global__ void k_deg(const int* __restrict__ rowptr, const int2* __restrict__ epack,
                      float* __restrict__ dinv) {
    int i = blockIdx.x * 256 + threadIdx.x;
    if (i >= NN) return;
    int p = rowptr[i], p1 = rowptr[i + 1];
    float deg = 1.0f;                      // self-loop weight
    for (; p < p1; ++p) deg += __int_as_float(epack[p].y);
    dinv[i] = rsqrtf(deg);                 // deg >= 1 always
}

// fp32 -> fp16 pre-scaled shadow in CHUNKED layout:
// chunk c (32 cols = 64B/node) stored contiguously: xh[c*CHUNK_U2 + node*8 + k]
__global__ void k_half(const float4* __restrict__ x4, const float* __restrict__ dinv,
                       uint2* __restrict__ xh) {
    int i = blockIdx.x * 256 + threadIdx.x;     // float4 index, NN*32 total
    if (i >= NN * 32) return;
    int node = i >> 5, j = i & 31;              // j: float4 group within row
    float di = dinv[node];
    float4 v = x4[i];
    __half2 h0 = __float22half2_rn(make_float2(di * v.x, di * v.y));
    __half2 h1 = __float22half2_rn(make_float2(di * v.z, di * v.w));
    uint2 pk;
    pk.x = *(const unsigned int*)&h0;
    pk.y = *(const unsigned int*)&h1;
    xh[(j >> 3) * CHUNK_U2 + node * 8 + (j & 7)] = pk;
}

// ---------- fused layer (chunked fp16 gather, fp32 accumulate/GEMM) ----------
// 32 rows/block, grid 1563, launch_bounds(256,4) (proven geometry; VGPR ~56).
// Gather runs as 4 COLUMN-CHUNK PHASES: phase c touches only chunk c (3.2 MB,
// fits each XCD's 4 MiB L2 regardless of src distribution -> L2-hit latency).
// Block = 32 streams of 8 lanes; stream = one dst row, 64B (one line) per gather;
// depth-8 pipeline pinned by sched_barrier(0); edge meta via nontemporal loads
// (streamed 4x, must not thrash the resident chunk).

#define CVT_FMA(GU, CBITS) do {                                              \
    const __half2* hp_ = (const __half2*)&(GU);                              \
    float2 f0_ = __half22float2(hp_[0]);                                     \
    float2 f1_ = __half22float2(hp_[1]);                                     \
    float cc_ = __int_as_float(CBITS);                                       \
    a.x = fmaf(cc_, f0_.x, a.x); a.y = fmaf(cc_, f0_.y, a.y);                \
    a.z = fmaf(cc_, f1_.x, a.z); a.w = fmaf(cc_, f1_.y, a.w);                \
} while (0)

#define GF8HC(EA0, EA1, EA2, EA3) do {                                       \
    uint2 g0 = xc[EA0.x * 8 + cl];                                           \
    uint2 g1 = xc[EA0.z * 8 + cl];                                           \
    uint2 g2 = xc[EA1.x * 8 + cl];                                           \
    uint2 g3 = xc[EA1.z * 8 + cl];                                           \
    uint2 g4 = xc[EA2.x * 8 + cl];                                           \
    uint2 g5 = xc[EA2.z * 8 + cl];                                           \
    uint2 g6 = xc[EA3.x * 8 + cl];                                           \
    uint2 g7 = xc[EA3.z * 8 + cl];                                           \
    __builtin_amdgcn_sched_barrier(0);                                       \
    CVT_FMA(g0, EA0.y); CVT_FMA(g1, EA0.w);                                  \
    CVT_FMA(g2, EA1.y); CVT_FMA(g3, EA1.w);                                  \
    CVT_FMA(g4, EA2.y); CVT_FMA(g5, EA2.w);                                  \
    CVT_FMA(g6, EA3.y); CVT_FMA(g7, EA3.w);                                  \
} while (0)

template<bool LEAKY, bool WRITE_HALF>
__global__ __launch_bounds__(256, 4)
void k_layer(const uint2* __restrict__ xh, const int2* __restrict__ epack,
             const int* __restrict__ rowptr, const float* __restrict__ dinv,
             const float* __restrict__ W, const float* __restrict__ b,
             uint2* __restrict__ outh, float* __restrict__ outf) {
    __shared__ float Xs[32][132];
    int tid = threadIdx.x;
    int row0 = blockIdx.x * 32;
    int st = tid >> 3;          // stream 0..31 (one dst row each)
    int cl = tid & 7;           // 8B column chunk within the 64B chunk-row

    int row = row0 + st;
    int p0 = 0, p1 = 0;
    float di = 0.f;
    if (row < NN) { p0 = rowptr[row]; p1 = rowptr[row + 1]; di = dinv[row]; }

    #pragma unroll 1
    for (int c = 0; c < 4; ++c) {
        const uint2* __restrict__ xc = xh + c * CHUNK_U2;
        if (row < NN) {
            uint2 sg = xc[row * 8 + cl];     // self term: y[row] (pre-scaled)
            const __half2* sp = (const __half2*)&sg;
            float2 s0 = __half22float2(sp[0]);
            float2 s1 = __half22float2(sp[1]);
            float4 a; a.x = s0.x; a.y = s0.y; a.z = s1.x; a.w = s1.y;
            int p = p0;
            if (p + 8 <= p1) {
                const iv4* q = (const iv4*)&epack[p];
                iv4 ea0 = __builtin_nontemporal_load(q);
                iv4 ea1 = __builtin_nontemporal_load(q + 1);
                iv4 ea2 = __builtin_nontemporal_load(q + 2);
                iv4 ea3 = __builtin_nontemporal_load(q + 3);
                p += 8;
                while (p + 8 <= p1) {
                    const iv4* q2 = (const iv4*)&epack[p];
                    iv4 eb0 = __builtin_nontemporal_load(q2);
                    iv4 eb1 = __builtin_nontemporal_load(q2 + 1);
                    iv4 eb2 = __builtin_nontemporal_load(q2 + 2);
                    iv4 eb3 = __builtin_nontemporal_load(q2 + 3);
                    GF8HC(ea0, ea1, ea2, ea3);
                    ea0 = eb0; ea1 = eb1; ea2 = eb2; ea3 = eb3;
                    p += 8;
                }
                GF8HC(ea0, ea1, ea2, ea3);
            }
            for (; p < p1; p += 2) {          // p stays even (padded counts)
                iv4 e = __builtin_nontemporal_load((const iv4*)&epack[p]);
                uint2 u0 = xc[e.x * 8 + cl];
                uint2 u1 = xc[e.z * 8 + cl];
                CVT_FMA(u0, e.y);
                CVT_FMA(u1, e.w);
            }
            a.x *= di; a.y *= di; a.z *= di; a.w *= di;   // fold dinv[dst]
            *(float4*)&Xs[st][c * 32 + cl * 4] = a;
        }
    }
    __syncthreads();

    // GEMM 32x128 (fp32)
    int tx = tid & 31, ty = tid >> 5;
    float acc[4][4] = {};
    for (int k = 0; k < DIM; k += 4) {
        float4 xv[4];
        #pragma unroll
        for (int r = 0; r < 4; ++r) xv[r] = *(const float4*)&Xs[ty * 4 + r][k];
        #pragma unroll
        for (int kk = 0; kk < 4; ++kk) {
            float4 wv2 = *(const float4*)&W[(k + kk) * DIM + tx * 4];
            #pragma unroll
            for (int r = 0; r < 4; ++r) {
                float xs = (&xv[r].x)[kk];
                acc[r][0] = fmaf(xs, wv2.x, acc[r][0]);
                acc[r][1] = fmaf(xs, wv2.y, acc[r][1]);
                acc[r][2] = fmaf(xs, wv2.z, acc[r][2]);
                acc[r][3] = fmaf(xs, wv2.w, acc[r][3]);
            }
        }
    }

    float4 bv = *(const float4*)&b[tx * 4];
    #pragma unroll
    for (int r = 0; r < 4; ++r) {
        int orow = row0 + ty * 4 + r;
        if (orow >= NN) continue;
        float4 v;
        v.x = acc[r][0] + bv.x; v.y = acc[r][1] + bv.y;
        v.z = acc[r][2] + bv.z; v.w = acc[r][3] + bv.w;
        if (LEAKY) {
            v.x = v.x > 0.f ? v.x : NEG_SLOPE * v.x;
            v.y = v.y > 0.f ? v.y : NEG_SLOPE * v.y;
            v.z = v.z > 0.f ? v.z : NEG_SLOPE * v.z;
            v.w = v.w > 0.f ? v.w : NEG_SLOPE * v.w;
        }
        if (WRITE_HALF) {
            float dd = dinv[orow];                     // pre-scale next layer's y
            __half2 h0 = __float22half2_rn(make_float2(dd * v.x, dd * v.y));
            __half2 h1 = __float22half2_rn(make_float2(dd * v.z, dd * v.w));
            uint2 pk;
            pk.x = *(const unsigned int*)&h0;
            pk.y = *(const unsigned int*)&h1;
            outh[(tx >> 3) * CHUNK_U2 + orow * 8 + (tx & 7)] = pk;   // chunked
        } else {
            *(float4*)&outf[orow * DIM + tx * 4] = v;
        }
    }
}

extern "C" void kernel_launch(void* const* d_in, const int* in_sizes, int n_in,
                              void* d_out, int out_size, void* d_ws, size_t ws_size,
                              hipStream_t stream) {
    const float* x     = (const float*)d_in[0];
    const int*   ei    = (const int*)d_in[1];
    const float* attr  = (const float*)d_in[2];
    const int*   etype = (const int*)d_in[3];
    const float* scale = (const float*)d_in[4];
    const float* W1 = (const float*)d_in[5];
    const float* b1 = (const float*)d_in[6];
    const float* W2 = (const float*)d_in[7];
    const float* b2 = (const float*)d_in[8];
    const float* W3 = (const float*)d_in[9];
    const float* b3 = (const float*)d_in[10];
    float* out = (float*)d_out;

    // ws layout (epack and hist adjacent -> one memset):
    uint2* xhA    = (uint2*)d_ws;               // NN*32 uint2 (12.8 MB, chunked)
    uint2* xhB    = xhA + NN * 32;              // NN*32 uint2 (12.8 MB, chunked)
    int2*  epack  = (int2*)(xhB + NN * 32);     // NEPAD packed edges (6.8 MB)
    int*   hist   = (int*)(epack + NEPAD);      // NN
    int*   slot   = hist + NN;                  // NE (3.2 MB)
    int*   rowptr = slot + NE;                  // NN+1
    float* dinv   = (float*)(rowptr + NN + 1);  // NN
    int*   aux    = (int*)(dinv + NN);          // 64

    const int nb_n = (NN + 255) / 256;          // 196
    const int nb_e = NE / 256;                  // 3125
    const int nb_l = (NN + 31) / 32;            // 1563
    const int nb_s1 = (NN + 1023) / 1024;       // 49
    const int nb_h = (NN * 32 + 255) / 256;

    (void)hipMemsetAsync(epack, 0, (size_t)NEPAD * sizeof(int2) + NN * sizeof(int), stream);
    k_hist<<<nb_e, 256, 0, stream>>>(ei, hist, slot);
    k_scan1<<<nb_s1, 256, 0, stream>>>(hist, rowptr, aux);
    k_scan3<<<nb_n, 256, 0, stream>>>(rowptr, aux);
    k_place<<<nb_e, 256, 0, stream>>>(ei, attr, etype, scale, rowptr, slot, epack);
    k_deg<<<nb_n, 256, 0, stream>>>(rowptr, epack, dinv);
    k_half<<<nb_h, 256, 0, stream>>>((const float4*)x, dinv, xhA);

    // layer 1: xhA -> xhB ; layer 2: xhB -> xhA ; layer 3: xhA -> d_out (fp32)
    k_layer<true,  true ><<<nb_l, 256, 0, stream>>>(xhA, epack, rowptr, dinv, W1, b1, xhB, nullptr);
    k_layer<true,  true ><<<nb_l, 256, 0, stream>>>(xhB, epack, rowptr, dinv, W2, b2, xhA, nullptr);
    k_layer<false, false><<<nb_l, 256, 0, stream>>>(xhA, epack, rowptr, dinv, W3, b3, nullptr, out);
}

// Round 12
// 255.175 us; speedup vs baseline: 1.2972x; 1.2972x over previous
//
#include <hip/hip_runtime.h>
#include <hip/hip_fp16.h>

#define NN 50000
#define NE 800000
#define NEPAD (NE + NN + 16)   // even-padded CSR capacity
#define DIM 128
#define NEG_SLOPE 0.1f

// ---------- preprocessing (atomic-light CSR build) ----------

// count histogram; atomic return value = within-row slot (saved for atomic-free place)
__global__ void k_hist(const int* __restrict__ ei, int* __restrict__ hist,
                       int* __restrict__ slot) {
    int e = blockIdx.x * 256 + threadIdx.x;
    if (e >= NE) return;
    int d = ei[NE + e];
    slot[e] = atomicAdd(&hist[d], 1);
}

// scan1: per-block (1024 elems) exclusive scan of EVEN-PADDED counts -> rowptr,
// block sums -> aux.
__global__ void k_scan1(const int* __restrict__ hist, int* __restrict__ rowptr,
                        int* __restrict__ aux) {
    __shared__ int sdata[256];
    int t = threadIdx.x;
    int base = blockIdx.x * 1024 + t * 4;
    int v[4]; int s = 0;
    #pragma unroll
    for (int j = 0; j < 4; ++j) {
        v[j] = (base + j < NN) ? ((hist[base + j] + 1) & ~1) : 0;  // pad to even
        s += v[j];
    }
    sdata[t] = s;
    __syncthreads();
    for (int off = 1; off < 256; off <<= 1) {
        int x = (t >= off) ? sdata[t - off] : 0;
        __syncthreads();
        sdata[t] += x;
        __syncthreads();
    }
    int run = sdata[t] - s;
    if (t == 255) aux[blockIdx.x] = sdata[255];
    #pragma unroll
    for (int j = 0; j < 4; ++j) { if (base + j < NN) rowptr[base + j] = run; run += v[j]; }
}

// scan3 (fused): every block redundantly scans the 49 block sums, adds offset;
// ALSO zeroes the single padding slot of odd-count rows (replaces 7 MB memset).
__global__ void k_scan3(int* __restrict__ rowptr, const int* __restrict__ hist,
                        const int* __restrict__ aux, int2* __restrict__ epack) {
    __shared__ int exs[64];
    __shared__ int stot;
    int t = threadIdx.x;
    if (t < 64) {
        int v = (t < 49) ? aux[t] : 0;
        int orig = v;
        for (int off = 1; off < 64; off <<= 1) {
            int y = __shfl_up(v, off, 64);
            if (t >= off) v += y;
        }
        exs[t] = v - orig;
        if (t == 48) stot = v;
    }
    __syncthreads();
    int i = blockIdx.x * 256 + t;
    if (i < NN) {
        int v = rowptr[i] + exs[i >> 10];
        rowptr[i] = v;
        int cnt = hist[i];
        if (cnt & 1) { int2 z; z.x = 0; z.y = 0; epack[v + cnt] = z; }  // pad slot
    }
    if (i == 0) rowptr[NN] = stot;
}

// atomic-free placement: epack[rowptr[d] + slot[e]] = {src, w}
__global__ void k_place(const int* __restrict__ ei, const float* __restrict__ attr,
                        const int* __restrict__ etype, const float* __restrict__ scale,
                        const int* __restrict__ rowptr, const int* __restrict__ slot,
                        int2* __restrict__ epack) {
    int e = blockIdx.x * 256 + threadIdx.x;
    if (e >= NE) return;
    int s = ei[e], d = ei[NE + e];
    float w = scale[etype[e]] * attr[e];
    int2 pk; pk.x = s; pk.y = __float_as_int(w);
    epack[rowptr[d] + slot[e]] = pk;
}

// fused deg + fp16 pre-scaled shadow: group of 32 lanes per node.
// dinv = rsqrt(1 + sum row coefs); xh[node] = fp16(dinv * x[node]).
__global__ __launch_bounds__(256)
void k_deghalf(const int* __restrict__ rowptr, const int2* __restrict__ epack,
               const float4* __restrict__ x4, float* __restrict__ dinv,
               uint2* __restrict__ xh) {
    int node = blockIdx.x * 8 + (threadIdx.x >> 5);   // grid 6250 exact
    int lane = threadIdx.x & 31;
    int p0 = rowptr[node], p1 = rowptr[node + 1];
    float c = 0.f;
    for (int p = p0 + lane; p < p1; p += 32) c += __int_as_float(epack[p].y);
    #pragma unroll
    for (int off = 16; off > 0; off >>= 1) c += __shfl_xor(c, off, 32);
    float di = rsqrtf(1.0f + c);                      // deg >= 1 (self-loop)
    if (lane == 0) dinv[node] = di;
    float4 v = x4[node * 32 + lane];
    __half2 h0 = __float22half2_rn(make_float2(di * v.x, di * v.y));
    __half2 h1 = __float22half2_rn(make_float2(di * v.z, di * v.w));
    uint2 pk;
    pk.x = *(const unsigned int*)&h0;
    pk.y = *(const unsigned int*)&h1;
    xh[node * 32 + lane] = pk;
}

// ---------- fused layer (fp16 pre-scaled gather, fp32 accumulate/GEMM) ----------
// PROVEN ROUND-8 KERNEL, BYTE-IDENTICAL: 32 rows/block, grid 1563,
// launch_bounds(256,4) -> VGPR ~56, depth-8 pinned pipeline, 2.3+ TB/s.

#define CVT_FMA(GU, CBITS) do {                                              \
    const __half2* hp_ = (const __half2*)&(GU);                              \
    float2 f0_ = __half22float2(hp_[0]);                                     \
    float2 f1_ = __half22float2(hp_[1]);                                     \
    float cc_ = __int_as_float(CBITS);                                       \
    a.x = fmaf(cc_, f0_.x, a.x); a.y = fmaf(cc_, f0_.y, a.y);                \
    a.z = fmaf(cc_, f1_.x, a.z); a.w = fmaf(cc_, f1_.y, a.w);                \
} while (0)

#define GF8H(EA0, EA1, EA2, EA3) do {                                        \
    uint2 g0 = xh[EA0.x * 32 + cl];                                          \
    uint2 g1 = xh[EA0.z * 32 + cl];                                          \
    uint2 g2 = xh[EA1.x * 32 + cl];                                          \
    uint2 g3 = xh[EA1.z * 32 + cl];                                          \
    uint2 g4 = xh[EA2.x * 32 + cl];                                          \
    uint2 g5 = xh[EA2.z * 32 + cl];                                          \
    uint2 g6 = xh[EA3.x * 32 + cl];                                          \
    uint2 g7 = xh[EA3.z * 32 + cl];                                          \
    __builtin_amdgcn_sched_barrier(0);                                       \
    CVT_FMA(g0, EA0.y); CVT_FMA(g1, EA0.w);                                  \
    CVT_FMA(g2, EA1.y); CVT_FMA(g3, EA1.w);                                  \
    CVT_FMA(g4, EA2.y); CVT_FMA(g5, EA2.w);                                  \
    CVT_FMA(g6, EA3.y); CVT_FMA(g7, EA3.w);                                  \
} while (0)

template<bool LEAKY, bool WRITE_HALF>
__global__ __launch_bounds__(256, 4)
void k_layer(const uint2* __restrict__ xh, const int2* __restrict__ epack,
             const int* __restrict__ rowptr, const float* __restrict__ dinv,
             const float* __restrict__ W, const float* __restrict__ b,
             uint2* __restrict__ outh, float* __restrict__ outf) {
    __shared__ float Xs[32][132];
    int tid = threadIdx.x;
    int row0 = blockIdx.x * 32;
    int st = tid >> 5;          // stream 0..7
    int cl = tid & 31;          // 8B column chunk within row (4 halves)

    #pragma unroll
    for (int rr = 0; rr < 4; ++rr) {
        int row = row0 + st * 4 + rr;
        if (row < NN) {
            float di = dinv[row];
            uint2 sg = xh[row * 32 + cl];     // self term: y[row] (pre-scaled)
            const __half2* sp = (const __half2*)&sg;
            float2 s0 = __half22float2(sp[0]);
            float2 s1 = __half22float2(sp[1]);
            float4 a; a.x = s0.x; a.y = s0.y; a.z = s1.x; a.w = s1.y;
            int p = rowptr[row], p1 = rowptr[row + 1];
            if (p + 8 <= p1) {
                const int4* q = (const int4*)&epack[p];
                int4 ea0 = q[0], ea1 = q[1], ea2 = q[2], ea3 = q[3];
                p += 8;
                while (p + 8 <= p1) {
                    const int4* q2 = (const int4*)&epack[p];
                    int4 eb0 = q2[0], eb1 = q2[1], eb2 = q2[2], eb3 = q2[3];
                    GF8H(ea0, ea1, ea2, ea3);
                    ea0 = eb0; ea1 = eb1; ea2 = eb2; ea3 = eb3;
                    p += 8;
                }
                GF8H(ea0, ea1, ea2, ea3);
            }
            for (; p < p1; p += 2) {          // p stays even (padded counts)
                int4 e = *(const int4*)&epack[p];
                uint2 u0 = xh[e.x * 32 + cl];
                uint2 u1 = xh[e.z * 32 + cl];
                CVT_FMA(u0, e.y);
                CVT_FMA(u1, e.w);
            }
            a.x *= di; a.y *= di; a.z *= di; a.w *= di;   // fold dinv[dst]
            *(float4*)&Xs[st * 4 + rr][cl * 4] = a;
        }
    }
    __syncthreads();

    // GEMM 32x128 (fp32)
    int tx = tid & 31, ty = tid >> 5;
    float acc[4][4] = {};
    for (int k = 0; k < DIM; k += 4) {
        float4 xv[4];
        #pragma unroll
        for (int r = 0; r < 4; ++r) xv[r] = *(const float4*)&Xs[ty * 4 + r][k];
        #pragma unroll
        for (int kk = 0; kk < 4; ++kk) {
            float4 wv2 = *(const float4*)&W[(k + kk) * DIM + tx * 4];
            #pragma unroll
            for (int r = 0; r < 4; ++r) {
                float xs = (&xv[r].x)[kk];
                acc[r][0] = fmaf(xs, wv2.x, acc[r][0]);
                acc[r][1] = fmaf(xs, wv2.y, acc[r][1]);
                acc[r][2] = fmaf(xs, wv2.z, acc[r][2]);
                acc[r][3] = fmaf(xs, wv2.w, acc[r][3]);
            }
        }
    }

    float4 bv = *(const float4*)&b[tx * 4];
    #pragma unroll
    for (int r = 0; r < 4; ++r) {
        int row = row0 + ty * 4 + r;
        if (row >= NN) continue;
        float4 v;
        v.x = acc[r][0] + bv.x; v.y = acc[r][1] + bv.y;
        v.z = acc[r][2] + bv.z; v.w = acc[r][3] + bv.w;
        if (LEAKY) {
            v.x = v.x > 0.f ? v.x : NEG_SLOPE * v.x;
            v.y = v.y > 0.f ? v.y : NEG_SLOPE * v.y;
            v.z = v.z > 0.f ? v.z : NEG_SLOPE * v.z;
            v.w = v.w > 0.f ? v.w : NEG_SLOPE * v.w;
        }
        if (WRITE_HALF) {
            float dd = dinv[row];                      // pre-scale next layer's y
            __half2 h0 = __float22half2_rn(make_float2(dd * v.x, dd * v.y));
            __half2 h1 = __float22half2_rn(make_float2(dd * v.z, dd * v.w));
            uint2 pk;
            pk.x = *(const unsigned int*)&h0;
            pk.y = *(const unsigned int*)&h1;
            outh[row * 32 + tx] = pk;
        } else {
            *(float4*)&outf[row * DIM + tx * 4] = v;
        }
    }
}

extern "C" void kernel_launch(void* const* d_in, const int* in_sizes, int n_in,
                              void* d_out, int out_size, void* d_ws, size_t ws_size,
                              hipStream_t stream) {
    const float* x     = (const float*)d_in[0];
    const int*   ei    = (const int*)d_in[1];
    const float* attr  = (const float*)d_in[2];
    const int*   etype = (const int*)d_in[3];
    const float* scale = (const float*)d_in[4];
    const float* W1 = (const float*)d_in[5];
    const float* b1 = (const float*)d_in[6];
    const float* W2 = (const float*)d_in[7];
    const float* b2 = (const float*)d_in[8];
    const float* W3 = (const float*)d_in[9];
    const float* b3 = (const float*)d_in[10];
    float* out = (float*)d_out;

    // ws layout:
    uint2* xhA    = (uint2*)d_ws;               // NN*32 uint2 (12.8 MB)
    uint2* xhB    = xhA + NN * 32;              // NN*32 uint2 (12.8 MB)
    int2*  epack  = (int2*)(xhB + NN * 32);     // NEPAD packed edges (6.8 MB)
    int*   hist   = (int*)(epack + NEPAD);      // NN
    int*   slot   = hist + NN;                  // NE (3.2 MB)
    int*   rowptr = slot + NE;                  // NN+1
    float* dinv   = (float*)(rowptr + NN + 1);  // NN
    int*   aux    = (int*)(dinv + NN);          // 64

    const int nb_n = (NN + 255) / 256;          // 196
    const int nb_e = NE / 256;                  // 3125
    const int nb_l = (NN + 31) / 32;            // 1563
    const int nb_s1 = (NN + 1023) / 1024;       // 49
    const int nb_dh = NN / 8;                   // 6250 (exact)

    (void)hipMemsetAsync(hist, 0, NN * sizeof(int), stream);   // hist only (200 KB)
    k_hist<<<nb_e, 256, 0, stream>>>(ei, hist, slot);
    k_scan1<<<nb_s1, 256, 0, stream>>>(hist, rowptr, aux);
    k_scan3<<<nb_n, 256, 0, stream>>>(rowptr, hist, aux, epack);   // + pad-slot zero
    k_place<<<nb_e, 256, 0, stream>>>(ei, attr, etype, scale, rowptr, slot, epack);
    k_deghalf<<<nb_dh, 256, 0, stream>>>(rowptr, epack, (const float4*)x, dinv, xhA);

    // layer 1: xhA -> xhB ; layer 2: xhB -> xhA ; layer 3: xhA -> d_out (fp32)
    k_layer<true,  true ><<<nb_l, 256, 0, stream>>>(xhA, epack, rowptr, dinv, W1, b1, xhB, nullptr);
    k_layer<true,  true ><<<nb_l, 256, 0, stream>>>(xhB, epack, rowptr, dinv, W2, b2, xhA, nullptr);
    k_layer<false, false><<<nb_l, 256, 0, stream>>>(xhA, epack, rowptr, dinv, W3, b3, nullptr, out);
}